// Round 11
// baseline (87.463 us; speedup 1.0000x reference)
//
#include <hip/hip_runtime.h>

// LocalAggregator: semantic splatting of P=2048 3D Gaussians onto a 60x60x36
// voxel grid (N=129600 points), C=13 channels.
//
// Round 11 strategy (R10 geometry + 2x TLP):
//   R5-R10 established: eval VALU ~5us, LDS ~9-15us, yet agg is stable at
//   ~27us and insensitive to 3x LDS traffic reduction -> latency-bound at
//   2.6 waves/SIMD, with phase serialization + block-count rounding tail.
//   Fix: same 675x(4x4x12) bricks, but 512 threads (8 waves):
//     - list splits 8 ways (~15 records/wave, half the serial chain)
//     - cull = 4 coalesced iters, build = 1 iter
//     - 5.3 waves/SIMD latency hiding; all 675 blocks co-resident
//       (1350 thr/CU, ~74KB LDS/CU)
//     - 8-way cross-wave reduce, 3 z-passes, overlay on record LDS
//   Record = 24 floats [mean, log2(opac), -0.5*log2e*icov (2x folded
//   off-diags), 13 sem, packed ent]; ent = g(11b)|xmask4<<11|ymask4<<15|
//   zmask12<<19; eval inbox = 2-op mask test; single v_exp_f32 per (rec,z).

constexpr int   HH      = 60;
constexpr int   WW      = 60;
constexpr int   DD      = 36;
constexpr int   P_N     = 2048;
constexpr int   C_N     = 13;
constexpr int   BXD     = 15;     // bricks in x (60/4)
constexpr int   BYD     = 15;     // bricks in y
constexpr int   BZD     = 3;      // bricks in z (36/12)
constexpr int   ZCH     = 12;     // z-extent per brick
constexpr int   NBRICK  = BXD * BYD * BZD;   // 675
constexpr int   CAP     = 256;    // survivor capacity (expected ~117, max ~170)
constexpr int   TPB     = 512;    // 8 waves
constexpr float GRID_SZ = 0.08f;

__global__ __launch_bounds__(TPB) void agg_fused(const float* __restrict__ means,
                                                 const float* __restrict__ opac,
                                                 const float* __restrict__ sem,
                                                 const float* __restrict__ scales,
                                                 const float* __restrict__ cov,
                                                 const float* __restrict__ origin,
                                                 float* __restrict__ out) {
    __shared__ int    s_idx[CAP];
    __shared__ int    s_cnt;
    // overlay: records CAP*6 float4 = 24.6KB  /  reduce [8][64][13] = 26.6KB
    __shared__ float4 s_mem[8 * 64 * C_N / 4];        // 26624 B
    float (*s_acc)[64][C_N] = (float (*)[64][C_N])s_mem;

    const int b = (int)blockIdx.x;
    const int bz = b % BZD;
    const int txy = b / BZD;
    const int bj = txy % BYD;
    const int bi = txy / BYD;
    const int i0 = bi * 4, j0 = bj * 4, k0 = bz * ZCH;

    const float ox = origin[0], oy = origin[1], oz = origin[2];

    if (threadIdx.x == 0) s_cnt = 0;
    __syncthreads();

    // --- a) cull: recompute box from raw means/scales (L1/L2-resident) ---
    for (int g = (int)threadIdx.x; g < P_N; g += TPB) {
        const float mx = means[g * 3 + 0], my = means[g * 3 + 1], mz = means[g * 3 + 2];
        const float sx = scales[g * 3 + 0], sy = scales[g * 3 + 1], sz = scales[g * 3 + 2];
        const float smax = fmaxf(sx, fmaxf(sy, sz));
        // match reference: ceil(smax*3.0/GRID), ((means-origin)/GRID) trunc
        const int rad = (int)ceilf(smax * 3.0f / GRID_SZ);
        const int mix = (int)((mx - ox) / GRID_SZ);
        const int miy = (int)((my - oy) / GRID_SZ);
        const int miz = (int)((mz - oz) / GRID_SZ);
        const bool ov = (mix - rad <= i0 + 3)       && (mix + rad >= i0)
                     && (miy - rad <= j0 + 3)       && (miy + rad >= j0)
                     && (miz - rad <= k0 + ZCH - 1) && (miz + rad >= k0);
        if (ov) {
            // per-axis masks: bit o set iff |brick0+o - center| <= rad
            int xlo = max(mix - rad - i0, 0), xhi = min(mix + rad - i0, 3);
            int ylo = max(miy - rad - j0, 0), yhi = min(miy + rad - j0, 3);
            int zlo = max(miz - rad - k0, 0), zhi = min(miz + rad - k0, ZCH - 1);
            unsigned mx4  = (0xFu >> (3 - xhi)) & (0xFu << xlo);
            unsigned my4  = (0xFu >> (3 - yhi)) & (0xFu << ylo);
            unsigned mz12 = (0xFFFu >> (ZCH - 1 - zhi)) & (0xFFFu << zlo);
            unsigned ent = (unsigned)g | (mx4 << 11) | (my4 << 15) | (mz12 << 19);
            int t = atomicAdd(&s_cnt, 1);
            if (t < CAP) s_idx[t] = (int)ent;
        }
    }
    __syncthreads();
    const int cnt = min(s_cnt, CAP);

    // --- b) build survivor records in LDS (thread e -> survivor e) ---
    for (int e = (int)threadIdx.x; e < cnt; e += TPB) {
        const int ent = s_idx[e];
        const int g = ent & 0x7FF;
        const float* cv = cov + g * 9;
        // packed = (xx, yy, zz, xy, yz, xz) = flat indices [0,4,8,1,5,2]
        const float a = cv[0], bb = cv[4], c = cv[8], d = cv[1], e5 = cv[5], f = cv[2];
        const float det = a * (bb * c - e5 * e5) - d * (d * c - e5 * f)
                        + f * (d * e5 - bb * f);
        const float kD = -0.5f * 1.44269504088896340736f;  // -0.5 * log2(e)
        const float kO = -1.44269504088896340736f;         // folds 2x off-diag
        float4 r0, r1, r2, r3, r4, r5;
        r0.x = means[g * 3 + 0]; r0.y = means[g * 3 + 1]; r0.z = means[g * 3 + 2];
        r0.w = __log2f(opac[g]);
        r1.x = kD * (bb * c - e5 * e5) / det;   // c_xx
        r1.y = kD * (a * c - f * f) / det;      // c_yy
        r1.z = kD * (a * bb - d * d) / det;     // c_zz
        r1.w = kO * (e5 * f - d * c) / det;     // c_xy
        r2.x = kO * (d * f - a * e5) / det;     // c_yz
        r2.y = kO * (d * e5 - bb * f) / det;    // c_xz
        const float* sm = sem + g * C_N;
        r2.z = sm[0];  r2.w = sm[1];
        r3.x = sm[2];  r3.y = sm[3];  r3.z = sm[4];  r3.w = sm[5];
        r4.x = sm[6];  r4.y = sm[7];  r4.z = sm[8];  r4.w = sm[9];
        r5.x = sm[10]; r5.y = sm[11]; r5.z = sm[12];
        r5.w = __int_as_float(ent);
        float4* dst = &s_mem[e * 6];
        dst[0] = r0; dst[1] = r1; dst[2] = r2; dst[3] = r3; dst[4] = r4; dst[5] = r5;
    }
    __syncthreads();

    // --- c) eval: lane owns 3 z-voxels; 8 waves split the list ---
    const int wave = (int)threadIdx.x >> 6;
    const int lane = (int)threadIdx.x & 63;
    const int kk = lane & 3, lj = (lane >> 2) & 3, li = lane >> 4;
    const int gi = i0 + li, gj = j0 + lj;
    // bit-exact replication of reference pts = (i + 0.5f) * GRID in fp32
    const float px = ((float)gi + 0.5f) * GRID_SZ;
    const float py = ((float)gj + 0.5f) * GRID_SZ;
    float    pzv[3];
    unsigned selv[3];
#pragma unroll
    for (int p = 0; p < 3; ++p) {
        pzv[p]  = ((float)(k0 + kk + 4 * p) + 0.5f) * GRID_SZ;
        selv[p] = (1u << (11 + li)) | (1u << (15 + lj)) | (1u << (19 + kk + 4 * p));
    }

    float acc[3][C_N];
#pragma unroll
    for (int p = 0; p < 3; ++p)
#pragma unroll
        for (int cc = 0; cc < C_N; ++cc) acc[p][cc] = 0.0f;

#pragma unroll 2
    for (int i = wave; i < cnt; i += 8) {
        const float4 r0 = s_mem[i * 6 + 0];   // mean.xyz, log2(opac)
        const float4 r1 = s_mem[i * 6 + 1];   // c_xx c_yy c_zz c_xy
        const float4 r2 = s_mem[i * 6 + 2];   // c_yz c_xz sem0 sem1
        const float4 r3 = s_mem[i * 6 + 3];   // sem2..5
        const float4 r4 = s_mem[i * 6 + 4];   // sem6..9
        const float4 r5 = s_mem[i * 6 + 5];   // sem10..12, packed ent
        const unsigned ent = (unsigned)__float_as_int(r5.w);
        const float dx = px - r0.x, dy = py - r0.y;
        // shared xy part of the base-2 exponent
        float base2 = r0.w;
        base2 = fmaf(r1.x, dx * dx, base2);
        base2 = fmaf(r1.y, dy * dy, base2);
        base2 = fmaf(r1.w, dx * dy, base2);
        float w[3];
#pragma unroll
        for (int p = 0; p < 3; ++p) {
            const float dz = pzv[p] - r0.z;
            float e2 = base2;
            e2 = fmaf(r1.z, dz * dz, e2);
            e2 = fmaf(r2.x, dy * dz, e2);
            e2 = fmaf(r2.y, dx * dz, e2);
            const float ww = __builtin_amdgcn_exp2f(e2);
            w[p] = ((ent & selv[p]) == selv[p]) ? ww : 0.0f;
        }
#pragma unroll
        for (int p = 0; p < 3; ++p) {
            acc[p][0]  = fmaf(w[p], r2.z, acc[p][0]);
            acc[p][1]  = fmaf(w[p], r2.w, acc[p][1]);
            acc[p][2]  = fmaf(w[p], r3.x, acc[p][2]);
            acc[p][3]  = fmaf(w[p], r3.y, acc[p][3]);
            acc[p][4]  = fmaf(w[p], r3.z, acc[p][4]);
            acc[p][5]  = fmaf(w[p], r3.w, acc[p][5]);
            acc[p][6]  = fmaf(w[p], r4.x, acc[p][6]);
            acc[p][7]  = fmaf(w[p], r4.y, acc[p][7]);
            acc[p][8]  = fmaf(w[p], r4.z, acc[p][8]);
            acc[p][9]  = fmaf(w[p], r4.w, acc[p][9]);
            acc[p][10] = fmaf(w[p], r5.x, acc[p][10]);
            acc[p][11] = fmaf(w[p], r5.y, acc[p][11]);
            acc[p][12] = fmaf(w[p], r5.z, acc[p][12]);
        }
    }

    // --- d) 3-pass 8-way cross-wave reduction (overlay on records) + store ---
#pragma unroll
    for (int p = 0; p < 3; ++p) {
        __syncthreads();   // records (p=0) / previous pass done before overlay
#pragma unroll
        for (int cc = 0; cc < C_N; ++cc) s_acc[wave][lane][cc] = acc[p][cc];
        __syncthreads();
        for (int t = (int)threadIdx.x; t < 64 * C_N; t += TPB) {
            const int v = t / C_N, c = t % C_N;
            const float s = s_acc[0][v][c] + s_acc[1][v][c]
                          + s_acc[2][v][c] + s_acc[3][v][c]
                          + s_acc[4][v][c] + s_acc[5][v][c]
                          + s_acc[6][v][c] + s_acc[7][v][c];
            const int vk = v & 3, vj = (v >> 2) & 3, vi = v >> 4;
            const long n = (long)(i0 + vi) * (WW * DD)
                         + (long)(j0 + vj) * DD + (k0 + vk + 4 * p);
            out[n * C_N + c] = s;
        }
    }
}

extern "C" void kernel_launch(void* const* d_in, const int* in_sizes, int n_in,
                              void* d_out, int out_size, void* d_ws, size_t ws_size,
                              hipStream_t stream) {
    const float* means  = (const float*)d_in[1];
    const float* opac   = (const float*)d_in[2];
    const float* sem    = (const float*)d_in[3];
    const float* scales = (const float*)d_in[4];
    const float* cov    = (const float*)d_in[5];
    const float* origin = (const float*)d_in[6];
    float* out = (float*)d_out;

    agg_fused<<<NBRICK, TPB, 0, stream>>>(means, opac, sem, scales, cov,
                                          origin, out);
}